// Round 14
// baseline (294.722 us; speedup 1.0000x reference)
//
#include <hip/hip_runtime.h>

// MADE / PixelCNN autoregressive inverse (all fp32, per reference).
//
// Ledger: r0-r4 6-bar/16-wave ~191-179us. r7 2-bar/8-wave 146.5. r9 MAC
// style irrelevant. r10 deep chain 229. r11 balanced helpers 137.8 (best).
// r13 1-dot-per-phase 143.9 (clean, no spill) -> slot time has a ~2.15us
// FLOOR independent of phase work/barrier count/wave count. Only remaining
// lever: fewer serial slots.
//
// r14: anti-diagonal wavefront. Dependencies: (i,j) needs (i,j-1) and
// (i-1,j+1) only -> schedule t = j + 2i: 22 slots (+1 drain), <=4 px/slot.
// 4 phases/slot:
//  P1: epi of D(t-1): net0 spines compute y from xchg (mu,ls raw sums),
//      write yb (single shared copy); net1 spine writes lsch[p] chunk.
//  P2: spines compute h0 for D(t) from yb (pads give border zeros).
//  P3: helpers: Ha s1a=W1nw+W1n | Hb s1b=W1ne+W1c | Hc s2a=W2nw+W2n |
//      Hd s2b=W2ne+W2w (FRAG+readlane dots, guards zero invalid taps);
//      spines: W1-W half-dots (SA elems 4q+0,1; SB 4q+2,3) -> r1wa/r1wb.
//  P4: spines (2 px each): h1=elu((bB+(s1a+s1b))+(r1wa+r1wb)) -> h1 grid;
//      c2 readlane on own h1v; h2=elu((c2+bC)+(s2a+s2b)); butterfly; xchg.
// h0/h1 grids: 5-row rings (row r last read t=2r+9 < first reuse 2r+10).
// All partials single-buffered (P3-write/P4-read same slot, barrier-ordered;
// next overwrite is 3 barriers later). x held lane-major in registers
// (lane p holds x[c][p]; epi uses readlane). LDS ~55KB. 12 waves (3/SIMD,
// ~170-reg budget), NO asm pins (r12 lesson: pins force spills).

#define NT 768

__device__ __forceinline__ float elu(float x) { return x > 0.f ? x : expm1f(x); }

__device__ __forceinline__ float rdlane(float v, int l) {
  return __int_as_float(__builtin_amdgcn_readlane(__float_as_int(v), l));
}

#define BAR() asm volatile("s_waitcnt lgkmcnt(0)\n\ts_barrier" ::: "memory")

#define DOT16(W_, F_)                                                \
  _Pragma("unroll")                                                  \
  for (int q = 0; q < 16; ++q) {                                     \
    a0 += (W_)[4*q+0] * rdlane((F_).x, q);                           \
    a1 += (W_)[4*q+1] * rdlane((F_).y, q);                           \
    a2 += (W_)[4*q+2] * rdlane((F_).z, q);                           \
    a3 += (W_)[4*q+3] * rdlane((F_).w, q);                           \
  }

#define FRAG(P_) (reinterpret_cast<const float4*>(P_)[ch & 15])
#define R5(r) ((r) < 5 ? (r) : (r) - 5)

__global__ __launch_bounds__(NT)
__attribute__((amdgpu_waves_per_eu(3, 3)))
void made_ar_decode_k(
    const float* __restrict__ x,
    const float* __restrict__ mw0, const float* __restrict__ mb0,
    const float* __restrict__ mw1, const float* __restrict__ mb1,
    const float* __restrict__ mw2, const float* __restrict__ mb2,
    const float* __restrict__ mwo, const float* __restrict__ mbo,
    const float* __restrict__ lw0, const float* __restrict__ lb0,
    const float* __restrict__ lw1, const float* __restrict__ lb1,
    const float* __restrict__ lw2, const float* __restrict__ lb2,
    const float* __restrict__ lwo, const float* __restrict__ lbo,
    float* __restrict__ out)
{
  const int b    = blockIdx.x;
  const int tid  = threadIdx.x;
  const int wv   = tid >> 6;     // 0..11
  const int net  = wv & 1;       // 0 = mu, 1 = lv
  const int role = wv >> 1;      // 0:SA 1:SB 2:Ha 3:Hb 4:Hc 5:Hd
  const int ch   = tid & 63;     // lane == out channel

  // 5-row rings, unpadded cols 0..7 (tap guards handle borders).
  __shared__ __align__(16) float h0g[2][5][8][64];  // [net][ring(i)][j][ch]
  __shared__ __align__(16) float h1g[2][5][8][64];
  __shared__ __align__(16) float yb[9][10][4];      // padded: prow=i+1, pcol=j+1
  __shared__ __align__(16) float xchg[2][4][4];     // [net][i&3][c] raw out sums
  __shared__ float s1a[4][2][64], s1b[4][2][64];    // W1: (nw+n), (ne+center)
  __shared__ float r1wa[4][2][64], r1wb[4][2][64];  // W1-W halves
  __shared__ float s2a[4][2][64], s2b[4][2][64];    // W2: (nw+n), (ne+w)
  __shared__ float lsch[64];

  for (int k = tid; k < 2*5*8*64; k += NT) {
    (&h0g[0][0][0][0])[k] = 0.f;
    (&h1g[0][0][0][0])[k] = 0.f;
  }
  for (int k = tid; k < 9*10*4; k += NT) (&yb[0][0][0])[k] = 0.f;
  if (tid < 64) lsch[tid] = 0.f;

  __syncthreads();

  if (role <= 1) {
    // ================= spines SA (e 0,1) / SB (e 2,3) =================
    const float* w0g = net ? lw0 : mw0;
    const float* w1g = net ? lw1 : mw1;
    const float* w2g = net ? lw2 : mw2;
    const float* wog = net ? lwo : mwo;
    float w0t[16], wc2[64], w1wh[32], wo4[4], xr[4];
    {
      const int KH[4] = {0,0,0,1};
      const int KW[4] = {0,1,2,0};
#pragma unroll
      for (int t4 = 0; t4 < 4; ++t4)
#pragma unroll
        for (int ic = 0; ic < 4; ++ic)
          w0t[t4*4+ic] = w0g[((ch*4 + ic)*3 + KH[t4])*3 + KW[t4]];
    }
#pragma unroll
    for (int q = 0; q < 64; ++q) wc2[q] = w2g[((ch*64 + q)*3 + 1)*3 + 1];
    const int hb = (role == 0) ? 0 : 2;   // W1-W half: elems 4q+hb, 4q+hb+1
#pragma unroll
    for (int q = 0; q < 16; ++q) {
      w1wh[2*q+0] = w1g[((ch*64 + 4*q + hb + 0)*3 + 1)*3 + 0];
      w1wh[2*q+1] = w1g[((ch*64 + 4*q + hb + 1)*3 + 1)*3 + 0];
    }
#pragma unroll
    for (int c = 0; c < 4; ++c) wo4[c] = wog[c*64 + ch];
#pragma unroll
    for (int c = 0; c < 4; ++c) xr[c] = x[b*256 + c*64 + ch];  // lane p holds x[c][p]
    const float bA = (net ? lb0 : mb0)[ch];
    const float bB = (net ? lb1 : mb1)[ch];
    const float bC = (net ? lb2 : mb2)[ch];
    float boM[4], boL[4];
#pragma unroll
    for (int c = 0; c < 4; ++c) { boM[c] = mbo[c]; boL[c] = lbo[c]; }
    const int e0 = (role == 0) ? 0 : 2;

#pragma unroll 1
    for (int t = 0; t <= 22; ++t) {
      const int ilo  = (t >= 8) ? ((t - 6) >> 1) : 0;
      int ihi = t >> 1; if (ihi > 7) ihi = 7;
      const int ilo1 = (t >= 9) ? ((t - 7) >> 1) : 0;
      int ihi1 = (t - 1) >> 1; if (ihi1 > 7) ihi1 = 7;

      // ---- P1: epi of D(t-1) ----
#pragma unroll
      for (int e = 0; e < 2; ++e) {
        const int i1 = ilo1 + e0 + e;
        if (t >= 1 && i1 <= ihi1) {
          const int j1 = t - 1 - 2*i1, pb = i1 & 3, p = 8*i1 + j1;
          const float4 l4 = *reinterpret_cast<const float4*>(&xchg[1][pb][0]);
          if (net == 0) {
            const float4 m4 = *reinterpret_cast<const float4*>(&xchg[0][pb][0]);
            float y0 = (rdlane(xr[0], p) - (m4.x + boM[0])) / (expf(0.5f*(l4.x + boL[0])) + 1e-12f);
            float y1 = (rdlane(xr[1], p) - (m4.y + boM[1])) / (expf(0.5f*(l4.y + boL[1])) + 1e-12f);
            float y2 = (rdlane(xr[2], p) - (m4.z + boM[2])) / (expf(0.5f*(l4.z + boL[2])) + 1e-12f);
            float y3 = (rdlane(xr[3], p) - (m4.w + boM[3])) / (expf(0.5f*(l4.w + boL[3])) + 1e-12f);
            if (ch == 0)
              *reinterpret_cast<float4*>(&yb[i1 + 1][j1 + 1][0]) = make_float4(y0, y1, y2, y3);
          } else {
            if (ch == 0)
              lsch[p] = 0.5f*((l4.x + boL[0]) + (l4.y + boL[1]) + (l4.z + boL[2]) + (l4.w + boL[3]));
          }
        }
      }
      BAR();

      // ---- P2: h0 of D(t) ----
#pragma unroll
      for (int e = 0; e < 2; ++e) {
        const int i = ilo + e0 + e;
        if (i <= ihi) {
          const int j = t - 2*i;
          const float4 yNW = *reinterpret_cast<const float4*>(&yb[i][j    ][0]);
          const float4 yN  = *reinterpret_cast<const float4*>(&yb[i][j + 1][0]);
          const float4 yNE = *reinterpret_cast<const float4*>(&yb[i][j + 2][0]);
          const float4 yW  = *reinterpret_cast<const float4*>(&yb[i + 1][j][0]);
          float acc = bA;
          acc += w0t[0]*yNW.x + w0t[1]*yNW.y + w0t[2]*yNW.z + w0t[3]*yNW.w;
          acc += w0t[4]*yN.x  + w0t[5]*yN.y  + w0t[6]*yN.z  + w0t[7]*yN.w;
          acc += w0t[8]*yNE.x + w0t[9]*yNE.y + w0t[10]*yNE.z + w0t[11]*yNE.w;
          acc += w0t[12]*yW.x + w0t[13]*yW.y + w0t[14]*yW.z + w0t[15]*yW.w;
          h0g[net][R5(i)][j][ch] = elu(acc);
        }
      }
      BAR();

      // ---- P3: W1-W half-dots for ALL valid px ----
#pragma unroll
      for (int e = 0; e < 4; ++e) {
        const int i = ilo + e;
        if (i <= ihi) {
          const int j = t - 2*i;
          float aa = 0.f, ab = 0.f;
          if (j >= 1) {
            const float4 f = FRAG(&h0g[net][R5(i)][j - 1][0]);
            const float fa = (role == 0) ? f.x : f.z;
            const float fb = (role == 0) ? f.y : f.w;
#pragma unroll
            for (int q = 0; q < 16; ++q) {
              aa += w1wh[2*q+0] * rdlane(fa, q);
              ab += w1wh[2*q+1] * rdlane(fb, q);
            }
          }
          (role == 0 ? r1wa : r1wb)[i & 3][net][ch] = aa + ab;
        }
      }
      BAR();

      // ---- P4: combine my px ----
#pragma unroll
      for (int e = 0; e < 2; ++e) {
        const int i = ilo + e0 + e;
        if (i <= ihi) {
          const int j = t - 2*i, pb = i & 3;
          const float h1v = elu((bB + (s1a[pb][net][ch] + s1b[pb][net][ch]))
                                + (r1wa[pb][net][ch] + r1wb[pb][net][ch]));
          h1g[net][R5(i)][j][ch] = h1v;
          float a0 = 0.f, a1 = 0.f, a2 = 0.f, a3 = 0.f;
#pragma unroll
          for (int q = 0; q < 16; ++q) {
            a0 += wc2[4*q+0] * rdlane(h1v, 4*q+0);
            a1 += wc2[4*q+1] * rdlane(h1v, 4*q+1);
            a2 += wc2[4*q+2] * rdlane(h1v, 4*q+2);
            a3 += wc2[4*q+3] * rdlane(h1v, 4*q+3);
          }
          const float c2 = (a0 + a1) + (a2 + a3);
          const float h2v = elu((c2 + bC) + (s2a[pb][net][ch] + s2b[pb][net][ch]));
          float s0 = wo4[0]*h2v, s1 = wo4[1]*h2v, s2 = wo4[2]*h2v, s3 = wo4[3]*h2v;
#pragma unroll
          for (int off = 32; off; off >>= 1) {
            s0 += __shfl_xor(s0, off, 64);
            s1 += __shfl_xor(s1, off, 64);
            s2 += __shfl_xor(s2, off, 64);
            s3 += __shfl_xor(s3, off, 64);
          }
          if (ch == 0)
            *reinterpret_cast<float4*>(&xchg[net][pb][0]) = make_float4(s0, s1, s2, s3);
        }
      }
      BAR();
    }

  } else {
    // ================= helpers Ha/Hb/Hc/Hd =================
    const float* w1g = net ? lw1 : mw1;
    const float* w2g = net ? lw2 : mw2;
    const float* wg = (role <= 3) ? w1g : w2g;
    int khA, kwA, khB, kwB;
    if      (role == 2) { khA = 0; kwA = 0; khB = 0; kwB = 1; }  // W1nw, W1n
    else if (role == 3) { khA = 0; kwA = 2; khB = 1; kwB = 1; }  // W1ne, W1c
    else if (role == 4) { khA = 0; kwA = 0; khB = 0; kwB = 1; }  // W2nw, W2n
    else                { khA = 0; kwA = 2; khB = 1; kwB = 0; }  // W2ne, W2w
    float wA[64], wB[64];
#pragma unroll
    for (int q = 0; q < 64; ++q) {
      wA[q] = wg[((ch*64 + q)*3 + khA)*3 + kwA];
      wB[q] = wg[((ch*64 + q)*3 + khB)*3 + kwB];
    }

#pragma unroll 1
    for (int t = 0; t <= 22; ++t) {
      const int ilo = (t >= 8) ? ((t - 6) >> 1) : 0;
      int ihi = t >> 1; if (ihi > 7) ihi = 7;

      BAR();   // end P1
      BAR();   // end P2

      // ---- P3: tap dots for all valid px of D(t) ----
#pragma unroll
      for (int e = 0; e < 4; ++e) {
        const int i = ilo + e;
        if (i <= ihi) {
          const int j = t - 2*i;
          float a0 = 0.f, a1 = 0.f, a2 = 0.f, a3 = 0.f;
          if (role == 2) {               // s1a = W1nw[i-1][j-1] + W1n[i-1][j]
            if (i >= 1) {
              const int r = R5(i - 1);
              if (j >= 1) { const float4 f = FRAG(&h0g[net][r][j - 1][0]); DOT16(wA, f); }
              { const float4 f = FRAG(&h0g[net][r][j][0]); DOT16(wB, f); }
            }
            s1a[i & 3][net][ch] = (a0 + a1) + (a2 + a3);
          } else if (role == 3) {        // s1b = W1ne[i-1][j+1] + W1c[i][j]
            if (i >= 1 && j <= 6) { const float4 f = FRAG(&h0g[net][R5(i - 1)][j + 1][0]); DOT16(wA, f); }
            { const float4 f = FRAG(&h0g[net][R5(i)][j][0]); DOT16(wB, f); }
            s1b[i & 3][net][ch] = (a0 + a1) + (a2 + a3);
          } else if (role == 4) {        // s2a = W2nw[i-1][j-1] + W2n[i-1][j]
            if (i >= 1) {
              const int r = R5(i - 1);
              if (j >= 1) { const float4 f = FRAG(&h1g[net][r][j - 1][0]); DOT16(wA, f); }
              { const float4 f = FRAG(&h1g[net][r][j][0]); DOT16(wB, f); }
            }
            s2a[i & 3][net][ch] = (a0 + a1) + (a2 + a3);
          } else {                       // s2b = W2ne[i-1][j+1] + W2w[i][j-1]
            if (i >= 1 && j <= 6) { const float4 f = FRAG(&h1g[net][R5(i - 1)][j + 1][0]); DOT16(wA, f); }
            if (j >= 1)           { const float4 f = FRAG(&h1g[net][R5(i)][j - 1][0]);     DOT16(wB, f); }
            s2b[i & 3][net][ch] = (a0 + a1) + (a2 + a3);
          }
        }
      }
      BAR();   // end P3
      BAR();   // end P4
    }
  }

  // yb complete (y(7,7) written in P1 of t=22); all barriers passed.
  if (tid < 256) {
    const int c = tid >> 6, p = tid & 63;
    out[(b*4 + c)*64 + p] = yb[(p >> 3) + 1][(p & 7) + 1][c];
  }
  if (tid == 0) {
    float s = 0.f;
    for (int p = 0; p < 64; ++p) s += lsch[p];   // raster-order fold (matches r13)
    out[32*4*64 + b] = s;
  }
}

extern "C" void kernel_launch(void* const* d_in, const int* in_sizes, int n_in,
                              void* d_out, int out_size, void* d_ws, size_t ws_size,
                              hipStream_t stream) {
  (void)in_sizes; (void)n_in; (void)out_size; (void)d_ws; (void)ws_size;
  made_ar_decode_k<<<dim3(32), dim3(NT), 0, stream>>>(
      (const float*)d_in[0],
      (const float*)d_in[1],  (const float*)d_in[2],
      (const float*)d_in[3],  (const float*)d_in[4],
      (const float*)d_in[5],  (const float*)d_in[6],
      (const float*)d_in[7],  (const float*)d_in[8],
      (const float*)d_in[9],  (const float*)d_in[10],
      (const float*)d_in[11], (const float*)d_in[12],
      (const float*)d_in[13], (const float*)d_in[14],
      (const float*)d_in[15], (const float*)d_in[16],
      (float*)d_out);
}

// Round 16
// 237.234 us; speedup vs baseline: 1.2423x; 1.2423x over previous
//
#include <hip/hip_runtime.h>

// MADE / PixelCNN autoregressive inverse (all fp32, per reference).
//
// Ledger: r0-r4 ~191-179us. r7 146.5. r11 balanced helpers 137.8 (best).
// r13 143.9 -> ~2.15us/slot floor. r14 anti-diagonal 214. r15 spin-flags:
// FAILED absmax 1.49 -- a real race: helper Ha is gated only on ROW-ABOVE
// flags, so it runs up to a row ahead of the spine, clobbering the 2-deep
// parity partial buffers; at j2=0/7 edges Hb/Hc also slip a row because the
// spine sets f0(p)/f1(p) BEFORE consuming slot p's partials.
//
// r16 = r15 with partial buffers deepened to 16 (indexed [target & 15]).
// Max producer lead proof: a helper's target p+16 (same slot, two rows
// down) requires a spine flag >= ~p+8, which the spine sets strictly after
// consuming slot p -> no clobber. xchg stays 2-deep (spines mutually gate
// to +-1 pixel, verified). sched_barrier(0) added after each poll (rule-18
// insurance against scheduler hoisting). Bounded polls (2^22) turn protocol
// bugs into wrong answers, not hangs. No reg pins (r12/r14 lesson).
// Dataflow = r11's proven 8-wave split, per net:
//  S  spine: epi(p-1) [y in-reg], h0, f0:=p, c1 | poll ha,hb: h1, f1:=p,
//     c2 | poll hc: h2, butterfly, xchg, xf:=p.
//  Ha {W1 NW,N,NE for p+1}   <- f0 row above
//  Hb {W1-W (f0(p)) + W2-NE (f1 row above) for p+1}
//  Hc {W2 NW,N (f1 row above) + W2-W (f1(p)) for p+1}

#define NT 512

__device__ __forceinline__ float elu(float x) { return x > 0.f ? x : expm1f(x); }

__device__ __forceinline__ float rdlane(float v, int l) {
  return __int_as_float(__builtin_amdgcn_readlane(__float_as_int(v), l));
}

__device__ __forceinline__ void poll_ge(volatile int* f, int v) {
  int g = 0;
  while (*f < v) { if (++g > (1 << 22)) break; }
  asm volatile("" ::: "memory");            // compiler fence
  __builtin_amdgcn_sched_barrier(0);        // scheduler fence (rule 18)
}

__device__ __forceinline__ void set_flag(volatile int* f, int v, bool lane0) {
  asm volatile("s_waitcnt lgkmcnt(0)" ::: "memory");  // drain data writes
  if (lane0) *f = v;
}

// 64-dot, activations broadcast via wave-uniform LDS float4 reads (r9 DOTU)
#define DOTU(W_, B_)                                                  \
  _Pragma("unroll")                                                   \
  for (int q = 0; q < 16; ++q) {                                      \
    const float4 hq = *reinterpret_cast<const float4*>((B_) + 4*q);   \
    a0 += (W_)[4*q+0] * hq.x;                                         \
    a1 += (W_)[4*q+1] * hq.y;                                         \
    a2 += (W_)[4*q+2] * hq.z;                                         \
    a3 += (W_)[4*q+3] * hq.w;                                         \
  }

__global__ __launch_bounds__(NT)
__attribute__((amdgpu_waves_per_eu(2, 2)))
void made_ar_decode_k(
    const float* __restrict__ x,
    const float* __restrict__ mw0, const float* __restrict__ mb0,
    const float* __restrict__ mw1, const float* __restrict__ mb1,
    const float* __restrict__ mw2, const float* __restrict__ mb2,
    const float* __restrict__ mwo, const float* __restrict__ mbo,
    const float* __restrict__ lw0, const float* __restrict__ lb0,
    const float* __restrict__ lw1, const float* __restrict__ lb1,
    const float* __restrict__ lw2, const float* __restrict__ lb2,
    const float* __restrict__ lwo, const float* __restrict__ lbo,
    float* __restrict__ out)
{
  const int b    = blockIdx.x;
  const int tid  = threadIdx.x;
  const int wv   = tid >> 6;       // 0..7
  const int net  = wv & 1;         // 0 = mu, 1 = lv
  const int role = wv >> 1;        // 0:S 1:Ha 2:Hb 3:Hc
  const int ch   = tid & 63;       // lane == out channel

  // row caches, parity-buffered by row; pcol = spatial col + 1; pads 0,9
  // never written -> permanent zeros ('SAME' border).
  __shared__ __align__(16) float h0row[2][2][10][64]; // [net][i&1][pcol][ch]
  __shared__ __align__(16) float h1row[2][2][10][64];
  __shared__ __align__(16) float yb[2][9][10][4];     // per-net private copy
  __shared__ __align__(16) float xchg[2][2][4];       // [net][p&1][c] raw sums
  __shared__ float s1n[16][2][64], s1w[16][2][64];    // [tgt&15][net][ch]
  __shared__ float s2ne[16][2][64], s2r[16][2][64];
  __shared__ int flg[12];  // 0+n:f0  2+n:f1  4+n:haf  6+n:hbf  8+n:hcf  10+n:xf

  for (int k = tid; k < 2*2*10*64; k += NT) {
    (&h0row[0][0][0][0])[k] = 0.f;
    (&h1row[0][0][0][0])[k] = 0.f;
  }
  for (int k = tid; k < 2*9*10*4; k += NT) (&yb[0][0][0][0])[k] = 0.f;
  for (int k = tid; k < 16*2*64; k += NT) {
    (&s1n[0][0][0])[k] = 0.f;  (&s1w[0][0][0])[k] = 0.f;
    (&s2ne[0][0][0])[k] = 0.f; (&s2r[0][0][0])[k] = 0.f;
  }
  if (tid < 12) flg[tid] = (tid < 4) ? -1 : (tid < 10 ? 0 : -1);

  __syncthreads();   // single init barrier; none in the loops

  volatile int* f0  = (volatile int*)&flg[0 + net];
  volatile int* f1  = (volatile int*)&flg[2 + net];
  volatile int* haf = (volatile int*)&flg[4 + net];
  volatile int* hbf = (volatile int*)&flg[6 + net];
  volatile int* hcf = (volatile int*)&flg[8 + net];
  volatile int* xfo = (volatile int*)&flg[10 + net];
  volatile int* xfx = (volatile int*)&flg[10 + (1 - net)];

  if (role == 0) {
    // ================= S: serial spine =================
    const float* w0g = net ? lw0 : mw0;
    const float* w1g = net ? lw1 : mw1;
    const float* w2g = net ? lw2 : mw2;
    const float* wog = net ? lwo : mwo;
    float w0t[16], wc1[64], wc2[64], wo4[4], xr[4];
    {
      const int KH[4] = {0,0,0,1};
      const int KW[4] = {0,1,2,0};
#pragma unroll
      for (int t4 = 0; t4 < 4; ++t4)
#pragma unroll
        for (int ic = 0; ic < 4; ++ic)
          w0t[t4*4+ic] = w0g[((ch*4 + ic)*3 + KH[t4])*3 + KW[t4]];
    }
#pragma unroll
    for (int q = 0; q < 64; ++q) wc1[q] = w1g[((ch*64 + q)*3 + 1)*3 + 1];
#pragma unroll
    for (int q = 0; q < 64; ++q) wc2[q] = w2g[((ch*64 + q)*3 + 1)*3 + 1];
#pragma unroll
    for (int c = 0; c < 4; ++c) wo4[c] = wog[c*64 + ch];
#pragma unroll
    for (int c = 0; c < 4; ++c) xr[c] = x[b*256 + c*64 + ch];  // lane p: x[c][p]
    const float bA = (net ? lb0 : mb0)[ch];
    const float bB = (net ? lb1 : mb1)[ch];
    const float bC = (net ? lb2 : mb2)[ch];
    float boM[4], boL[4];
#pragma unroll
    for (int c = 0; c < 4; ++c) { boM[c] = mbo[c]; boL[c] = lbo[c]; }

    float os0 = 0.f, os1 = 0.f, os2 = 0.f, os3 = 0.f;  // own raw sums (prev px)
    float y0 = 0.f, y1 = 0.f, y2 = 0.f, y3 = 0.f;      // y(p-1)
    float lsacc = 0.f;

#pragma unroll 1
    for (int p = 0; p < 64; ++p) {
      const int i = p >> 3, j = p & 7, cur = i & 1, pb = p & 15;

      // ---- epi(p-1): own sums in regs, other net's via xchg ----
      if (p > 0) {
        const int pp = p - 1, qb = pp & 1;
        poll_ge(xfx, pp);
        const float4 o4 = *reinterpret_cast<const float4*>(&xchg[1 - net][qb][0]);
        const float m0 = net ? o4.x : os0, m1 = net ? o4.y : os1;
        const float m2 = net ? o4.z : os2, m3 = net ? o4.w : os3;
        const float l0 = net ? os0 : o4.x, l1 = net ? os1 : o4.y;
        const float l2 = net ? os2 : o4.z, l3 = net ? os3 : o4.w;
        y0 = (rdlane(xr[0], pp) - (m0 + boM[0])) / (expf(0.5f*(l0 + boL[0])) + 1e-12f);
        y1 = (rdlane(xr[1], pp) - (m1 + boM[1])) / (expf(0.5f*(l1 + boL[1])) + 1e-12f);
        y2 = (rdlane(xr[2], pp) - (m2 + boM[2])) / (expf(0.5f*(l2 + boL[2])) + 1e-12f);
        y3 = (rdlane(xr[3], pp) - (m3 + boM[3])) / (expf(0.5f*(l3 + boL[3])) + 1e-12f);
        if (ch == 0)
          *reinterpret_cast<float4*>(&yb[net][(pp>>3)+1][(pp&7)+1][0]) =
              make_float4(y0, y1, y2, y3);
      }

      // ---- h0(p): N-taps from yb (padded rows), W-tap in-register ----
      float acc = bA;
      {
        const float4 yNW = *reinterpret_cast<const float4*>(&yb[net][i][j    ][0]);
        const float4 yN  = *reinterpret_cast<const float4*>(&yb[net][i][j + 1][0]);
        const float4 yNE = *reinterpret_cast<const float4*>(&yb[net][i][j + 2][0]);
        acc += w0t[0]*yNW.x + w0t[1]*yNW.y + w0t[2]*yNW.z + w0t[3]*yNW.w;
        acc += w0t[4]*yN.x  + w0t[5]*yN.y  + w0t[6]*yN.z  + w0t[7]*yN.w;
        acc += w0t[8]*yNE.x + w0t[9]*yNE.y + w0t[10]*yNE.z + w0t[11]*yNE.w;
        if (j > 0) acc += w0t[12]*y0 + w0t[13]*y1 + w0t[14]*y2 + w0t[15]*y3;
      }
      const float h0v = elu(acc);
      h0row[net][cur][j + 1][ch] = h0v;
      set_flag(f0, p, ch == 0);

      // ---- c1: readlane chain on own h0v ----
      float c1;
      {
        float a0 = 0.f, a1 = 0.f, a2 = 0.f, a3 = 0.f;
#pragma unroll
        for (int q = 0; q < 16; ++q) {
          a0 += wc1[4*q+0] * rdlane(h0v, 4*q+0);
          a1 += wc1[4*q+1] * rdlane(h0v, 4*q+1);
          a2 += wc1[4*q+2] * rdlane(h0v, 4*q+2);
          a3 += wc1[4*q+3] * rdlane(h0v, 4*q+3);
        }
        c1 = (a0 + a1) + (a2 + a3);
      }

      poll_ge(haf, p);
      poll_ge(hbf, p);
      const float h1v = elu(((c1 + bB) + s1n[pb][net][ch]) + s1w[pb][net][ch]);
      h1row[net][cur][j + 1][ch] = h1v;
      set_flag(f1, p, ch == 0);

      // ---- c2 ----
      float c2;
      {
        float a0 = 0.f, a1 = 0.f, a2 = 0.f, a3 = 0.f;
#pragma unroll
        for (int q = 0; q < 16; ++q) {
          a0 += wc2[4*q+0] * rdlane(h1v, 4*q+0);
          a1 += wc2[4*q+1] * rdlane(h1v, 4*q+1);
          a2 += wc2[4*q+2] * rdlane(h1v, 4*q+2);
          a3 += wc2[4*q+3] * rdlane(h1v, 4*q+3);
        }
        c2 = (a0 + a1) + (a2 + a3);
      }

      poll_ge(hcf, p);
      const float h2v = elu(((c2 + bC) + s2ne[pb][net][ch]) + s2r[pb][net][ch]);

      float s0 = wo4[0]*h2v, s1 = wo4[1]*h2v, s2 = wo4[2]*h2v, s3 = wo4[3]*h2v;
#pragma unroll
      for (int off = 32; off; off >>= 1) {
        s0 += __shfl_xor(s0, off, 64);
        s1 += __shfl_xor(s1, off, 64);
        s2 += __shfl_xor(s2, off, 64);
        s3 += __shfl_xor(s3, off, 64);
      }
      os0 = s0; os1 = s1; os2 = s2; os3 = s3;
      if (ch == 0)
        *reinterpret_cast<float4*>(&xchg[net][p & 1][0]) = make_float4(s0, s1, s2, s3);
      set_flag(xfo, p, ch == 0);
      if (net == 1)
        lsacc += 0.5f*((s0 + boL[0]) + (s1 + boL[1]) + (s2 + boL[2]) + (s3 + boL[3]));
    }

    // ---- final epi(63) + output ----
    poll_ge(xfx, 63);
    {
      const float4 o4 = *reinterpret_cast<const float4*>(&xchg[1 - net][1][0]);
      const float m0 = net ? o4.x : os0, m1 = net ? o4.y : os1;
      const float m2 = net ? o4.z : os2, m3 = net ? o4.w : os3;
      const float l0 = net ? os0 : o4.x, l1 = net ? os1 : o4.y;
      const float l2 = net ? os2 : o4.z, l3 = net ? os3 : o4.w;
      float fy0 = (rdlane(xr[0], 63) - (m0 + boM[0])) / (expf(0.5f*(l0 + boL[0])) + 1e-12f);
      float fy1 = (rdlane(xr[1], 63) - (m1 + boM[1])) / (expf(0.5f*(l1 + boL[1])) + 1e-12f);
      float fy2 = (rdlane(xr[2], 63) - (m2 + boM[2])) / (expf(0.5f*(l2 + boL[2])) + 1e-12f);
      float fy3 = (rdlane(xr[3], 63) - (m3 + boM[3])) / (expf(0.5f*(l3 + boL[3])) + 1e-12f);
      if (ch == 0)
        *reinterpret_cast<float4*>(&yb[net][8][8][0]) = make_float4(fy0, fy1, fy2, fy3);
    }
    if (net == 0) {
      // copy-out from own yb (same-wave writes; compiler orders via lgkmcnt)
#pragma unroll
      for (int c = 0; c < 4; ++c)
        out[(b*4 + c)*64 + ch] = yb[0][(ch >> 3) + 1][(ch & 7) + 1][c];
    } else if (ch == 0) {
      out[32*4*64 + b] = lsacc;
    }

  } else if (role == 1) {
    // ============ Ha: W1 {NW,N,NE} for p+1 -> s1n ============
    const float* w1g = net ? lw1 : mw1;
    float wnw[64], wn[64], wne[64];
#pragma unroll
    for (int q = 0; q < 64; ++q) {
      wnw[q] = w1g[((ch*64 + q)*3 + 0)*3 + 0];
      wn [q] = w1g[((ch*64 + q)*3 + 0)*3 + 1];
      wne[q] = w1g[((ch*64 + q)*3 + 0)*3 + 2];
    }
#pragma unroll 1
    for (int p = 0; p < 63; ++p) {
      const int p2 = p + 1, i2 = p2 >> 3, j2 = p2 & 7;
      float v = 0.f;
      if (i2 >= 1) {
        const int nfl = 8*(i2 - 1) + ((j2 < 7) ? j2 + 1 : 7);
        poll_ge(f0, nfl);
        const int sp = (i2 - 1) & 1;
        float a0 = 0.f, a1 = 0.f, a2 = 0.f, a3 = 0.f;
        DOTU(wnw, &h0row[net][sp][j2    ][0]);
        DOTU(wn,  &h0row[net][sp][j2 + 1][0]);
        DOTU(wne, &h0row[net][sp][j2 + 2][0]);
        v = (a0 + a1) + (a2 + a3);
      }
      s1n[p2 & 15][net][ch] = v;
      set_flag(haf, p2, ch == 0);
    }

  } else if (role == 2) {
    // ============ Hb: W1-W for p+1 + W2-NE for p+1 ============
    const float* w1g = net ? lw1 : mw1;
    const float* w2g = net ? lw2 : mw2;
    float w1w[64], w2ne[64];
#pragma unroll
    for (int q = 0; q < 64; ++q) {
      w1w [q] = w1g[((ch*64 + q)*3 + 1)*3 + 0];
      w2ne[q] = w2g[((ch*64 + q)*3 + 0)*3 + 2];
    }
#pragma unroll 1
    for (int p = 0; p < 63; ++p) {
      const int p2 = p + 1, i2 = p2 >> 3, j2 = p2 & 7;
      float v1 = 0.f, v2 = 0.f;
      if (j2 >= 1) {                       // W1-W tap = h0(p)
        poll_ge(f0, p);
        float a0 = 0.f, a1 = 0.f, a2 = 0.f, a3 = 0.f;
        DOTU(w1w, &h0row[net][i2 & 1][j2][0]);
        v1 = (a0 + a1) + (a2 + a3);
      }
      if (i2 >= 1) {                       // W2-NE from h1 row i2-1
        const int nfl = 8*(i2 - 1) + ((j2 < 7) ? j2 + 1 : 7);
        poll_ge(f1, nfl);
        float a0 = 0.f, a1 = 0.f, a2 = 0.f, a3 = 0.f;
        DOTU(w2ne, &h1row[net][(i2 - 1) & 1][j2 + 2][0]);
        v2 = (a0 + a1) + (a2 + a3);
      }
      s1w [p2 & 15][net][ch] = v1;
      s2ne[p2 & 15][net][ch] = v2;
      set_flag(hbf, p2, ch == 0);
    }

  } else {
    // ============ Hc: W2 {NW,N} + W2-W for p+1 -> s2r ============
    const float* w2g = net ? lw2 : mw2;
    float w2nw[64], w2n[64], w2w[64];
#pragma unroll
    for (int q = 0; q < 64; ++q) {
      w2nw[q] = w2g[((ch*64 + q)*3 + 0)*3 + 0];
      w2n [q] = w2g[((ch*64 + q)*3 + 0)*3 + 1];
      w2w [q] = w2g[((ch*64 + q)*3 + 1)*3 + 0];
    }
#pragma unroll 1
    for (int p = 0; p < 63; ++p) {
      const int p2 = p + 1, i2 = p2 >> 3, j2 = p2 & 7;
      float a0 = 0.f, a1 = 0.f, a2 = 0.f, a3 = 0.f;
      if (i2 >= 1) {
        poll_ge(f1, 8*(i2 - 1) + j2);      // N-taps: h1 row i2-1 up to col j2
        const int sp = (i2 - 1) & 1;
        DOTU(w2nw, &h1row[net][sp][j2    ][0]);
        DOTU(w2n,  &h1row[net][sp][j2 + 1][0]);
      }
      if (j2 >= 1) {                       // W2-W tap = h1(p)
        poll_ge(f1, p);
        DOTU(w2w, &h1row[net][i2 & 1][j2][0]);
      }
      s2r[p2 & 15][net][ch] = (a0 + a1) + (a2 + a3);
      set_flag(hcf, p2, ch == 0);
    }
  }
}

extern "C" void kernel_launch(void* const* d_in, const int* in_sizes, int n_in,
                              void* d_out, int out_size, void* d_ws, size_t ws_size,
                              hipStream_t stream) {
  (void)in_sizes; (void)n_in; (void)out_size; (void)d_ws; (void)ws_size;
  made_ar_decode_k<<<dim3(32), dim3(NT), 0, stream>>>(
      (const float*)d_in[0],
      (const float*)d_in[1],  (const float*)d_in[2],
      (const float*)d_in[3],  (const float*)d_in[4],
      (const float*)d_in[5],  (const float*)d_in[6],
      (const float*)d_in[7],  (const float*)d_in[8],
      (const float*)d_in[9],  (const float*)d_in[10],
      (const float*)d_in[11], (const float*)d_in[12],
      (const float*)d_in[13], (const float*)d_in[14],
      (const float*)d_in[15], (const float*)d_in[16],
      (float*)d_out);
}